// Round 19
// baseline (64.143 us; speedup 1.0000x reference)
//
#include <hip/hip_runtime.h>
#include <math.h>

// R19 = R18 + prologue/tail pipelining (same playbook as R18's epilogue):
//  (a) Wenc fragments hoisted to kernel start (hidden under staging-store wait + P1),
//      Wq fragments hoisted before P2 (two barriers of hiding),
//  (b) argmax global loads issued before E4 (3 barriers early; consumed after E6).
// Pure reorderings; no new sync. Peak regs unchanged in the agent loop.

typedef __attribute__((ext_vector_type(8))) short bf16x8;
typedef __attribute__((ext_vector_type(4))) float f32x4;
typedef __attribute__((ext_vector_type(4))) __bf16 bf16x4f;

#define PITCH 136   // bf16 pitch: 272B rows
#define TRB 32

__device__ __forceinline__ float lrelu(float x){ return x > 0.f ? x : 0.01f * x; }

__device__ __forceinline__ unsigned short f2bf(float x){   // wprep only
    union { float f; unsigned u; } c; c.f = x;
    unsigned u = c.u; u += 0x7fffu + ((u >> 16) & 1u);
    return (unsigned short)(u >> 16);
}
__device__ __forceinline__ ushort4 pack4v(f32x4 v){
    union { bf16x4f b; ushort4 u; } c;
    c.b = __builtin_convertvector(v, bf16x4f);   // 2x v_cvt_pk_bf16_f32
    return c.u;
}
__device__ __forceinline__ f32x4 ldg_nt4(const float* p){
    return __builtin_nontemporal_load((const f32x4*)p);
}

// fragment-packed weight load: chunk (m-tile, kc) is 512 bf16 (1KB), lane-major.
__device__ __forceinline__ bf16x8 ldA(const unsigned short* __restrict__ WT, int Kc,
                                      int m0, int kc, int lane){
    return *(const bf16x8*)(WT + ((((size_t)(m0 >> 4)) * Kc + kc) << 9) + lane * 8);
}
__device__ __forceinline__ bf16x8 ldB(const unsigned short* L, int n0, int kc, int lane){
    return *(const bf16x8*)(L + (n0 + (lane & 15)) * PITCH + kc * 32 + (lane >> 4) * 8);
}

template<int NKC>
__device__ __forceinline__ void ldW(const unsigned short* __restrict__ WT, int Kc, int M0,
                                    int kc0, int lane, bf16x8 F[2][NKC]){
#pragma unroll
    for (int mt = 0; mt < 2; ++mt)
#pragma unroll
        for (int kc = 0; kc < NKC; ++kc)
            F[mt][kc] = ldA(WT, Kc, M0 + mt * 16, kc0 + kc, lane);
}

template<int NKC>
__device__ __forceinline__ void mmR(const bf16x8 F[2][NKC], const unsigned short* Ls,
                                    int lane, f32x4 acc[2][2]){
    __builtin_amdgcn_s_setprio(1);
#pragma unroll
    for (int kc = 0; kc < NKC; ++kc) {
        bf16x8 b[2];
#pragma unroll
        for (int nt = 0; nt < 2; ++nt) b[nt] = ldB(Ls, nt * 16, kc, lane);
#pragma unroll
        for (int mt = 0; mt < 2; ++mt)
#pragma unroll
            for (int nt = 0; nt < 2; ++nt)
                acc[mt][nt] = __builtin_amdgcn_mfma_f32_16x16x32_bf16(F[mt][kc], b[nt], acc[mt][nt], 0, 0, 0);
    }
    __builtin_amdgcn_s_setprio(0);
}

template<int NKC>
__device__ __forceinline__ void mmG(const unsigned short* __restrict__ WT, int Kc, int M0,
                                    int kc0, const unsigned short* Ls, int lane,
                                    f32x4 acc[2][2]){
    bf16x8 F[2][NKC];
    ldW<NKC>(WT, Kc, M0, kc0, lane, F);
    mmR<NKC>(F, Ls, lane, acc);
}

// staging loads (non-temporal, f32 in regs); n = -1 => s_i
__device__ __forceinline__ void ld_sa_f(const float* __restrict__ s, const float* __restrict__ a,
                                        int row0, int n, int t, f32x4 sf[3], f32x4& af){
#pragma unroll
    for (int i = 0; i < 3; ++i) {
        int idx = t + 256 * i; int r = idx / 24, c4 = idx % 24;
        sf[i] = ldg_nt4(s + (size_t)(row0 + r) * 768 + 96 + 96 * n + c4 * 4);
    }
    af = ldg_nt4(a + (size_t)(row0 + (t >> 3)) * 256 + 32 + 32 * n + (t & 7) * 4);
}
__device__ __forceinline__ void st_sa(unsigned short* buf, int t,
                                      const f32x4 sf[3], const f32x4 af){
#pragma unroll
    for (int i = 0; i < 3; ++i) {
        int idx = t + 256 * i; int r = idx / 24, c4 = idx % 24;
        *(ushort4*)(buf + r * PITCH + c4 * 4) = pack4v(sf[i]);
    }
    *(ushort4*)(buf + (t >> 3) * PITCH + 96 + (t & 7) * 4) = pack4v(af);
}

// destination offset of element (q=out_row, f=in_col) in fragment-packed layout
__device__ __forceinline__ int froff(int q, int f, int Kc){
    return (((q >> 4) * Kc + (f >> 5)) << 9) + (((f >> 3) & 3) << 7) + ((q & 15) << 3) + (f & 7);
}

// ---- weight prep: fp32 W[in][out] -> bf16 fragment-packed W^T in d_ws ----
__global__ void wprep(const float* __restrict__ Ws, const float* __restrict__ Wsa,
                      const float* __restrict__ Wq_, const float* __restrict__ Wk_,
                      const float* __restrict__ Wv_, const float* __restrict__ Wo_,
                      const float* __restrict__ W1, const float* __restrict__ W2,
                      unsigned short* __restrict__ o)
{
    int id = blockIdx.x * 256 + threadIdx.x;
    if (id >= 229376) return;
    float v; int dst;
    if (id < 12288)        { int q = id / 96, f = id - q * 96;
                             v = Ws[f * 128 + q];              dst = froff(q, f, 3); }
    else if (id < 126976)  { int li = id - 12288; int n = li >> 14; int r = li & 16383;
                             int q = r >> 7, f = r & 127;
                             v = Wsa[n * 16384 + f * 128 + q]; dst = 12288 + n * 16384 + froff(q, f, 4); }
    else if (id < 143360)  { int li = id - 126976; int q = li >> 7, f = li & 127;
                             v = Wq_[f * 128 + q];             dst = 126976 + froff(q, f, 4); }
    else if (id < 159744)  { int li = id - 143360; int q = li >> 7, f = li & 127;
                             v = Wk_[f * 128 + q];             dst = 143360 + froff(q, f, 4); }
    else if (id < 176128)  { int li = id - 159744; int q = li >> 7, f = li & 127;
                             v = Wv_[f * 128 + q];             dst = 159744 + froff(q, f, 4); }
    else if (id < 192512)  { int li = id - 176128; int q = li >> 7, f = li & 127;
                             v = Wo_[f * 128 + q];             dst = 176128 + froff(q, f, 4); }
    else if (id < 225280)  { int li = id - 192512; int q = li >> 8, f = li & 255;
                             v = W1[f * 128 + q];              dst = 192512 + froff(q, f, 8); }
    else                   { int li = id - 225280; int q = li >> 7, f = li & 127;
                             v = W2[f * 32 + q];               dst = 225280 + froff(q, f, 4); }
    o[dst] = f2bf(v);
}

__global__ void __launch_bounds__(256, 2)
ac_mfma(const float* __restrict__ s, const float* __restrict__ a,
        const unsigned short* __restrict__ WS,
        const float* __restrict__ b_enc_s, const float* __restrict__ b_enc_sa,
        const float* __restrict__ bv, const float* __restrict__ bo,
        const float* __restrict__ b_fc1, const float* __restrict__ b_fc2,
        float* __restrict__ out_q, float* __restrict__ out_allq)
{
    // 5 x 8704B buffers = 43,520 B
    __shared__ __align__(16) unsigned short SMEM[5 * TRB * PITCH];
    unsigned short* bufA0 = SMEM;                     // staging even-parity / attn / h1
    unsigned short* bufA1 = SMEM + TRB * PITCH;       // staging odd-parity ; P-overlay
    unsigned short* sE0   = SMEM + 2 * TRB * PITCH;   // e(even) / ov ; P-overlay
    unsigned short* sE1   = SMEM + 3 * TRB * PITCH;   // e(odd)
    unsigned short* sENC  = SMEM + 4 * TRB * PITCH;   // s_enc ; S-overlay

    const int t = threadIdx.x, lane = t & 63, wid = t >> 6;
    const int l15 = lane & 15, l4 = lane >> 4;
    const int M0 = 32 * wid;
    const int row0 = blockIdx.x * TRB;
    const float rsd = 0.17677669529663687f;  // 1/sqrt(32)

    const unsigned short* WencST = WS;
    const unsigned short* WsaT   = WS + 12288;
    const unsigned short* WqT    = WS + 126976;
    const unsigned short* WkT    = WS + 143360;
    const unsigned short* WvT    = WS + 159744;
    const unsigned short* WoT    = WS + 176128;
    const unsigned short* W1T    = WS + 192512;
    const unsigned short* W2T    = WS + 225280;

    f32x4 sf[3]; f32x4 af;

    // ---- prologue: Wenc frags first (hidden under staging wait + P1), stage s_i ----
    bf16x8 WeF[2][3];
    ldW<3>(WencST, 3, M0, 0, lane, WeF);
    ld_sa_f(s, a, row0, -1, t, sf, af);
    st_sa(bufA0, t, sf, af);
    __syncthreads();                            // P1

    // ---- s_enc = lrelu(s_i @ Wenc_s + b) (frags already in regs) ----
    f32x4 acc[2][2];
#pragma unroll
    for (int mt = 0; mt < 2; ++mt)
#pragma unroll
        for (int nt = 0; nt < 2; ++nt) acc[mt][nt] = (f32x4){0.f, 0.f, 0.f, 0.f};
    mmR<3>(WeF, bufA0, lane, acc);
    bf16x8 WqF[2][4];
    ldW<4>(WqT, 4, M0, 0, lane, WqF);           // prefetch Wq (used after P3)
    ld_sa_f(s, a, row0, 0, t, sf, af);          // issue agent-0 staging loads
    __syncthreads();                            // P2: enc reads of bufA0 done
#pragma unroll
    for (int mt = 0; mt < 2; ++mt) {
        float4 bb = *(const float4*)(b_enc_s + M0 + mt * 16 + l4 * 4);
#pragma unroll
        for (int nt = 0; nt < 2; ++nt) {
            f32x4 v;
            v[0] = lrelu(acc[mt][nt][0] + bb.x); v[1] = lrelu(acc[mt][nt][1] + bb.y);
            v[2] = lrelu(acc[mt][nt][2] + bb.z); v[3] = lrelu(acc[mt][nt][3] + bb.w);
            *(ushort4*)(sENC + (nt * 16 + l15) * PITCH + M0 + mt * 16 + l4 * 4) = pack4v(v);
        }
    }
    st_sa(bufA1, t, sf, af);                    // staging(0) -> bufA1
    __syncthreads();                            // P3: sENC + staging(0) visible

    // ---- Q (frags prefetched; wave wid == head wid) ----
    f32x4 q[2][2];
#pragma unroll
    for (int mt = 0; mt < 2; ++mt)
#pragma unroll
        for (int nt = 0; nt < 2; ++nt) q[mt][nt] = (f32x4){0.f, 0.f, 0.f, 0.f};
    mmR<4>(WqF, sENC, lane, q);

    // ---- hoist Wk/Wv fragments for the whole agent loop (64 regs) ----
    bf16x8 WkF[2][4], WvF[2][4];
    ldW<4>(WkT, 4, M0, 0, lane, WkF);
    ldW<4>(WvT, 4, M0, 0, lane, WvF);

    float4 bvf[2];
#pragma unroll
    for (int mt = 0; mt < 2; ++mt) bvf[mt] = *(const float4*)(bv + M0 + mt * 16 + l4 * 4);

    f32x4 atn[2][2];
#pragma unroll
    for (int mt = 0; mt < 2; ++mt)
#pragma unroll
        for (int nt = 0; nt < 2; ++nt) atn[mt][nt] = (f32x4){0.f, 0.f, 0.f, 0.f};
    float m_[2] = {-INFINITY, -INFINITY}, l_[2] = {0.f, 0.f};

    // merged K+V + online-softmax for one e-tile (frags in regs; single LDS pass)
    auto kv_phase = [&](const unsigned short* EB){
        f32x4 kk[2][2], vv[2][2];
#pragma unroll
        for (int mt = 0; mt < 2; ++mt)
#pragma unroll
            for (int nt = 0; nt < 2; ++nt) {
                kk[mt][nt] = (f32x4){0.f, 0.f, 0.f, 0.f};
                vv[mt][nt] = (f32x4){0.f, 0.f, 0.f, 0.f};
            }
        __builtin_amdgcn_s_setprio(1);
#pragma unroll
        for (int kc = 0; kc < 4; ++kc) {
            bf16x8 b[2];
#pragma unroll
            for (int nt = 0; nt < 2; ++nt) b[nt] = ldB(EB, nt * 16, kc, lane);
#pragma unroll
            for (int mt = 0; mt < 2; ++mt)
#pragma unroll
                for (int nt = 0; nt < 2; ++nt) {
                    kk[mt][nt] = __builtin_amdgcn_mfma_f32_16x16x32_bf16(WkF[mt][kc], b[nt], kk[mt][nt], 0, 0, 0);
                    vv[mt][nt] = __builtin_amdgcn_mfma_f32_16x16x32_bf16(WvF[mt][kc], b[nt], vv[mt][nt], 0, 0, 0);
                }
        }
        __builtin_amdgcn_s_setprio(0);
        float pr[2], corr[2];
#pragma unroll
        for (int nt = 0; nt < 2; ++nt) {
            float p = 0.f;
#pragma unroll
            for (int mt = 0; mt < 2; ++mt)
#pragma unroll
                for (int r = 0; r < 4; ++r) p = fmaf(q[mt][nt][r], kk[mt][nt][r], p);
            p += __shfl_xor(p, 16);
            p += __shfl_xor(p, 32);
            float sc = p * rsd;
            float mo = m_[nt], mn = fmaxf(mo, sc);
            pr[nt]   = __expf(sc - mn);
            corr[nt] = __expf(mo - mn);
            l_[nt] = l_[nt] * corr[nt] + pr[nt];
            m_[nt] = mn;
        }
#pragma unroll
        for (int mt = 0; mt < 2; ++mt)
#pragma unroll
            for (int nt = 0; nt < 2; ++nt)
#pragma unroll
                for (int r = 0; r < 4; ++r) {
                    float vx = lrelu(vv[mt][nt][r] + ((const float*)&bvf[mt])[r]);
                    atn[mt][nt][r] = fmaf(atn[mt][nt][r], corr[nt], pr[nt] * vx);
                }
    };

    // ---- agent loop: ONE barrier per iteration ----
    for (int n = 0; n < 7; ++n) {
        unsigned short* stageRd = (n & 1) ? bufA0 : bufA1;
        unsigned short* stageWr = (n & 1) ? bufA1 : bufA0;
        unsigned short* eWr     = (n & 1) ? sE1 : sE0;
        unsigned short* eRd     = (n & 1) ? sE0 : sE1;

        if (n < 6) ld_sa_f(s, a, row0, n + 1, t, sf, af);   // issue nt loads early
        bf16x8 F[2][4];
        ldW<4>(WsaT + n * 16384, 4, M0, 0, lane, F);        // issue Wsa(n) frags

        if (n) kv_phase(eRd);                               // KV(n-1) under the loads

        f32x4 e[2][2];
#pragma unroll
        for (int mt = 0; mt < 2; ++mt)
#pragma unroll
            for (int nt = 0; nt < 2; ++nt) e[mt][nt] = (f32x4){0.f, 0.f, 0.f, 0.f};
        mmR<4>(F, stageRd, lane, e);

#pragma unroll
        for (int mt = 0; mt < 2; ++mt) {
            float4 bb = *(const float4*)(b_enc_sa + n * 128 + M0 + mt * 16 + l4 * 4);
#pragma unroll
            for (int nt = 0; nt < 2; ++nt) {
                f32x4 v;
                v[0] = lrelu(e[mt][nt][0] + bb.x); v[1] = lrelu(e[mt][nt][1] + bb.y);
                v[2] = lrelu(e[mt][nt][2] + bb.z); v[3] = lrelu(e[mt][nt][3] + bb.w);
                *(ushort4*)(eWr + (nt * 16 + l15) * PITCH + M0 + mt * 16 + l4 * 4) = pack4v(v);
            }
        }
        if (n < 6) st_sa(stageWr, t, sf, af);
        __syncthreads();                        // the one barrier
    }
    kv_phase(sE0);                              // agent 6 (e(6) is in sE0)

    // ---- epilogue pipelining: prefetch Wo frags; h1 half-1 from sENC (stable) ----
    bf16x8 WoF[2][4];
    ldW<4>(WoT, 4, M0, 0, lane, WoF);
    f32x4 hacc[2][2];
#pragma unroll
    for (int mt = 0; mt < 2; ++mt)
#pragma unroll
        for (int nt = 0; nt < 2; ++nt) hacc[mt][nt] = (f32x4){0.f, 0.f, 0.f, 0.f};
    mmG<4>(W1T, 8, M0, 0, sENC, lane, hacc);    // h1 k=0..127 (overlaps E1 region)

    // ---- attn normalize -> bufA0 ----
#pragma unroll
    for (int mt = 0; mt < 2; ++mt)
#pragma unroll
        for (int nt = 0; nt < 2; ++nt) {
            float inv = 1.f / l_[nt];
            f32x4 v;
            v[0] = atn[mt][nt][0] * inv; v[1] = atn[mt][nt][1] * inv;
            v[2] = atn[mt][nt][2] * inv; v[3] = atn[mt][nt][3] * inv;
            *(ushort4*)(bufA0 + (nt * 16 + l15) * PITCH + M0 + mt * 16 + l4 * 4) = pack4v(v);
        }
    __syncthreads();                            // E1

    // ---- prefetch W1 half-2 frags; ov = attn @ Wo + bo -> sE0 ----
    bf16x8 W1F[2][4];
    ldW<4>(W1T, 8, M0, 4, lane, W1F);
#pragma unroll
    for (int mt = 0; mt < 2; ++mt)
#pragma unroll
        for (int nt = 0; nt < 2; ++nt) acc[mt][nt] = (f32x4){0.f, 0.f, 0.f, 0.f};
    mmR<4>(WoF, bufA0, lane, acc);
#pragma unroll
    for (int mt = 0; mt < 2; ++mt) {
        float4 bb = *(const float4*)(bo + M0 + mt * 16 + l4 * 4);
#pragma unroll
        for (int nt = 0; nt < 2; ++nt) {
            f32x4 v;
            v[0] = acc[mt][nt][0] + bb.x; v[1] = acc[mt][nt][1] + bb.y;
            v[2] = acc[mt][nt][2] + bb.z; v[3] = acc[mt][nt][3] + bb.w;
            *(ushort4*)(sE0 + (nt * 16 + l15) * PITCH + M0 + mt * 16 + l4 * 4) = pack4v(v);
        }
    }
    __syncthreads();                            // E2

    // ---- h1 half-2 (ov in sE0, frags prefetched) -> bufA0 ----
    mmR<4>(W1F, sE0, lane, hacc);
    // prefetch fc2 fragments (used after E4)
    bf16x8 a0 = ldA(W2T, 4, 0, wid, lane);
    bf16x8 a1 = ldA(W2T, 4, 16, wid, lane);
    // early-issue argmax loads (consumed after E6)
    f32x4 av[8];
    if (t < TRB) {
#pragma unroll
        for (int jj = 0; jj < 8; ++jj)
            av[jj] = ldg_nt4(a + (size_t)(row0 + t) * 256 + jj * 4);
    }
#pragma unroll
    for (int mt = 0; mt < 2; ++mt) {
        float4 bb = *(const float4*)(b_fc1 + M0 + mt * 16 + l4 * 4);
#pragma unroll
        for (int nt = 0; nt < 2; ++nt) {
            f32x4 v;
            v[0] = lrelu(hacc[mt][nt][0] + bb.x); v[1] = lrelu(hacc[mt][nt][1] + bb.y);
            v[2] = lrelu(hacc[mt][nt][2] + bb.z); v[3] = lrelu(hacc[mt][nt][3] + bb.w);
            *(ushort4*)(bufA0 + (nt * 16 + l15) * PITCH + M0 + mt * 16 + l4 * 4) = pack4v(v);
        }
    }
    __syncthreads();                            // E4: h1 visible

    // ---- all_q = h1 @ W_fc2 + b2 : wave wid takes K-chunk kc=wid ----
    float* P = (float*)(SMEM + TRB * PITCH);    // 16KB overlay on bufA1+sE0 (dead)
    {
        bf16x8 b0 = ldB(bufA0, 0, wid, lane);
        bf16x8 b1 = ldB(bufA0, 16, wid, lane);
        f32x4 z = (f32x4){0.f, 0.f, 0.f, 0.f};
        f32x4 c00 = __builtin_amdgcn_mfma_f32_16x16x32_bf16(a0, b0, z, 0, 0, 0);
        f32x4 c01 = __builtin_amdgcn_mfma_f32_16x16x32_bf16(a0, b1, z, 0, 0, 0);
        f32x4 c10 = __builtin_amdgcn_mfma_f32_16x16x32_bf16(a1, b0, z, 0, 0, 0);
        f32x4 c11 = __builtin_amdgcn_mfma_f32_16x16x32_bf16(a1, b1, z, 0, 0, 0);
        *(f32x4*)(P + wid * 1024 + (l15     ) * 32 +      l4 * 4) = c00;
        *(f32x4*)(P + wid * 1024 + (16 + l15) * 32 +      l4 * 4) = c01;
        *(f32x4*)(P + wid * 1024 + (l15     ) * 32 + 16 + l4 * 4) = c10;
        *(f32x4*)(P + wid * 1024 + (16 + l15) * 32 + 16 + l4 * 4) = c11;
    }
    __syncthreads();                            // E5

    float* S = (float*)sENC;                    // stash [32][33] overlay (sENC dead)
#pragma unroll
    for (int j = 0; j < 4; ++j) {
        int o = t + 256 * j; int row = o >> 5, f = o & 31;
        float v = P[row * 32 + f] + P[1024 + row * 32 + f]
                + P[2048 + row * 32 + f] + P[3072 + row * 32 + f] + b_fc2[f];
        out_allq[(size_t)(row0 + row) * 32 + f] = v;
        S[row * 33 + f] = v;
    }
    __syncthreads();                            // E6

    // ---- q = all_q[argmax(a[:, :32])] (loads already in regs) ----
    if (t < TRB) {
        float best = -INFINITY; int bi = 0;
#pragma unroll
        for (int jj = 0; jj < 8; ++jj) {
#pragma unroll
            for (int e2 = 0; e2 < 4; ++e2)
                if (av[jj][e2] > best) { best = av[jj][e2]; bi = jj * 4 + e2; }
        }
        out_q[row0 + t] = S[t * 33 + bi];
    }
}

extern "C" void kernel_launch(void* const* d_in, const int* in_sizes, int n_in,
                              void* d_out, int out_size, void* d_ws, size_t ws_size,
                              hipStream_t stream)
{
    (void)n_in; (void)out_size; (void)ws_size;
    const float* s        = (const float*)d_in[0];
    const float* a        = (const float*)d_in[1];
    const float* W_enc_s  = (const float*)d_in[2];
    const float* b_enc_s  = (const float*)d_in[3];
    const float* W_enc_sa = (const float*)d_in[4];
    const float* b_enc_sa = (const float*)d_in[5];
    const float* Wq       = (const float*)d_in[6];
    const float* Wk       = (const float*)d_in[7];
    const float* Wv       = (const float*)d_in[8];
    const float* bv       = (const float*)d_in[9];
    const float* Wo       = (const float*)d_in[10];
    const float* bo       = (const float*)d_in[11];
    const float* W_fc1    = (const float*)d_in[12];
    const float* b_fc1    = (const float*)d_in[13];
    const float* W_fc2    = (const float*)d_in[14];
    const float* b_fc2    = (const float*)d_in[15];

    int B = in_sizes[0] / 768;
    float* out_q    = (float*)d_out;
    float* out_allq = out_q + B;
    unsigned short* WS = (unsigned short*)d_ws;

    wprep<<<dim3(896), dim3(256), 0, stream>>>(W_enc_s, W_enc_sa, Wq, Wk, Wv, Wo,
                                               W_fc1, W_fc2, WS);
    ac_mfma<<<dim3(B / TRB), dim3(256), 0, stream>>>(s, a, WS, b_enc_s, b_enc_sa,
                                                     bv, bo, b_fc1, b_fc2,
                                                     out_q, out_allq);
}

// Round 20
// 62.841 us; speedup vs baseline: 1.0207x; 1.0207x over previous
//
#include <hip/hip_runtime.h>
#include <math.h>

// FINAL (= R18, best measured: 62.96us, 9.7x over the fp32 baseline).
// R19's prologue/tail pipelining was null-to-negative -> reverted.
// Structure: TRB=32, 4 waves (M-slice 32 feats/wave = 1 head), fragment-packed
// bf16 weights in d_ws, nt activation loads, 1 barrier/agent, merged K+V pass,
// Wk/Wv frags register-hoisted, epilogue software-pipelined.
// Floor evidence: no pipe >25%; occupancy/tile/barrier/bank/setprio levers all
// isolated and resolved (null or spill) across R3-R19.

typedef __attribute__((ext_vector_type(8))) short bf16x8;
typedef __attribute__((ext_vector_type(4))) float f32x4;
typedef __attribute__((ext_vector_type(4))) __bf16 bf16x4f;

#define PITCH 136   // bf16 pitch: 272B rows
#define TRB 32

__device__ __forceinline__ float lrelu(float x){ return x > 0.f ? x : 0.01f * x; }

__device__ __forceinline__ unsigned short f2bf(float x){   // wprep only
    union { float f; unsigned u; } c; c.f = x;
    unsigned u = c.u; u += 0x7fffu + ((u >> 16) & 1u);
    return (unsigned short)(u >> 16);
}
__device__ __forceinline__ ushort4 pack4v(f32x4 v){
    union { bf16x4f b; ushort4 u; } c;
    c.b = __builtin_convertvector(v, bf16x4f);   // 2x v_cvt_pk_bf16_f32
    return c.u;
}
__device__ __forceinline__ f32x4 ldg_nt4(const float* p){
    return __builtin_nontemporal_load((const f32x4*)p);
}

// fragment-packed weight load: chunk (m-tile, kc) is 512 bf16 (1KB), lane-major.
__device__ __forceinline__ bf16x8 ldA(const unsigned short* __restrict__ WT, int Kc,
                                      int m0, int kc, int lane){
    return *(const bf16x8*)(WT + ((((size_t)(m0 >> 4)) * Kc + kc) << 9) + lane * 8);
}
__device__ __forceinline__ bf16x8 ldB(const unsigned short* L, int n0, int kc, int lane){
    return *(const bf16x8*)(L + (n0 + (lane & 15)) * PITCH + kc * 32 + (lane >> 4) * 8);
}

template<int NKC>
__device__ __forceinline__ void ldW(const unsigned short* __restrict__ WT, int Kc, int M0,
                                    int kc0, int lane, bf16x8 F[2][NKC]){
#pragma unroll
    for (int mt = 0; mt < 2; ++mt)
#pragma unroll
        for (int kc = 0; kc < NKC; ++kc)
            F[mt][kc] = ldA(WT, Kc, M0 + mt * 16, kc0 + kc, lane);
}

template<int NKC>
__device__ __forceinline__ void mmR(const bf16x8 F[2][NKC], const unsigned short* Ls,
                                    int lane, f32x4 acc[2][2]){
    __builtin_amdgcn_s_setprio(1);
#pragma unroll
    for (int kc = 0; kc < NKC; ++kc) {
        bf16x8 b[2];
#pragma unroll
        for (int nt = 0; nt < 2; ++nt) b[nt] = ldB(Ls, nt * 16, kc, lane);
#pragma unroll
        for (int mt = 0; mt < 2; ++mt)
#pragma unroll
            for (int nt = 0; nt < 2; ++nt)
                acc[mt][nt] = __builtin_amdgcn_mfma_f32_16x16x32_bf16(F[mt][kc], b[nt], acc[mt][nt], 0, 0, 0);
    }
    __builtin_amdgcn_s_setprio(0);
}

template<int NKC>
__device__ __forceinline__ void mmG(const unsigned short* __restrict__ WT, int Kc, int M0,
                                    int kc0, const unsigned short* Ls, int lane,
                                    f32x4 acc[2][2]){
    bf16x8 F[2][NKC];
    ldW<NKC>(WT, Kc, M0, kc0, lane, F);
    mmR<NKC>(F, Ls, lane, acc);
}

// staging loads (non-temporal, f32 in regs); n = -1 => s_i
__device__ __forceinline__ void ld_sa_f(const float* __restrict__ s, const float* __restrict__ a,
                                        int row0, int n, int t, f32x4 sf[3], f32x4& af){
#pragma unroll
    for (int i = 0; i < 3; ++i) {
        int idx = t + 256 * i; int r = idx / 24, c4 = idx % 24;
        sf[i] = ldg_nt4(s + (size_t)(row0 + r) * 768 + 96 + 96 * n + c4 * 4);
    }
    af = ldg_nt4(a + (size_t)(row0 + (t >> 3)) * 256 + 32 + 32 * n + (t & 7) * 4);
}
__device__ __forceinline__ void st_sa(unsigned short* buf, int t,
                                      const f32x4 sf[3], const f32x4 af){
#pragma unroll
    for (int i = 0; i < 3; ++i) {
        int idx = t + 256 * i; int r = idx / 24, c4 = idx % 24;
        *(ushort4*)(buf + r * PITCH + c4 * 4) = pack4v(sf[i]);
    }
    *(ushort4*)(buf + (t >> 3) * PITCH + 96 + (t & 7) * 4) = pack4v(af);
}

// destination offset of element (q=out_row, f=in_col) in fragment-packed layout
__device__ __forceinline__ int froff(int q, int f, int Kc){
    return (((q >> 4) * Kc + (f >> 5)) << 9) + (((f >> 3) & 3) << 7) + ((q & 15) << 3) + (f & 7);
}

// ---- weight prep: fp32 W[in][out] -> bf16 fragment-packed W^T in d_ws ----
__global__ void wprep(const float* __restrict__ Ws, const float* __restrict__ Wsa,
                      const float* __restrict__ Wq_, const float* __restrict__ Wk_,
                      const float* __restrict__ Wv_, const float* __restrict__ Wo_,
                      const float* __restrict__ W1, const float* __restrict__ W2,
                      unsigned short* __restrict__ o)
{
    int id = blockIdx.x * 256 + threadIdx.x;
    if (id >= 229376) return;
    float v; int dst;
    if (id < 12288)        { int q = id / 96, f = id - q * 96;
                             v = Ws[f * 128 + q];              dst = froff(q, f, 3); }
    else if (id < 126976)  { int li = id - 12288; int n = li >> 14; int r = li & 16383;
                             int q = r >> 7, f = r & 127;
                             v = Wsa[n * 16384 + f * 128 + q]; dst = 12288 + n * 16384 + froff(q, f, 4); }
    else if (id < 143360)  { int li = id - 126976; int q = li >> 7, f = li & 127;
                             v = Wq_[f * 128 + q];             dst = 126976 + froff(q, f, 4); }
    else if (id < 159744)  { int li = id - 143360; int q = li >> 7, f = li & 127;
                             v = Wk_[f * 128 + q];             dst = 143360 + froff(q, f, 4); }
    else if (id < 176128)  { int li = id - 159744; int q = li >> 7, f = li & 127;
                             v = Wv_[f * 128 + q];             dst = 159744 + froff(q, f, 4); }
    else if (id < 192512)  { int li = id - 176128; int q = li >> 7, f = li & 127;
                             v = Wo_[f * 128 + q];             dst = 176128 + froff(q, f, 4); }
    else if (id < 225280)  { int li = id - 192512; int q = li >> 8, f = li & 255;
                             v = W1[f * 128 + q];              dst = 192512 + froff(q, f, 8); }
    else                   { int li = id - 225280; int q = li >> 7, f = li & 127;
                             v = W2[f * 32 + q];               dst = 225280 + froff(q, f, 4); }
    o[dst] = f2bf(v);
}

__global__ void __launch_bounds__(256, 2)
ac_mfma(const float* __restrict__ s, const float* __restrict__ a,
        const unsigned short* __restrict__ WS,
        const float* __restrict__ b_enc_s, const float* __restrict__ b_enc_sa,
        const float* __restrict__ bv, const float* __restrict__ bo,
        const float* __restrict__ b_fc1, const float* __restrict__ b_fc2,
        float* __restrict__ out_q, float* __restrict__ out_allq)
{
    // 5 x 8704B buffers = 43,520 B
    __shared__ __align__(16) unsigned short SMEM[5 * TRB * PITCH];
    unsigned short* bufA0 = SMEM;                     // staging even-parity / attn / h1
    unsigned short* bufA1 = SMEM + TRB * PITCH;       // staging odd-parity ; P-overlay
    unsigned short* sE0   = SMEM + 2 * TRB * PITCH;   // e(even) / ov ; P-overlay
    unsigned short* sE1   = SMEM + 3 * TRB * PITCH;   // e(odd)
    unsigned short* sENC  = SMEM + 4 * TRB * PITCH;   // s_enc ; S-overlay

    const int t = threadIdx.x, lane = t & 63, wid = t >> 6;
    const int l15 = lane & 15, l4 = lane >> 4;
    const int M0 = 32 * wid;
    const int row0 = blockIdx.x * TRB;
    const float rsd = 0.17677669529663687f;  // 1/sqrt(32)

    const unsigned short* WencST = WS;
    const unsigned short* WsaT   = WS + 12288;
    const unsigned short* WqT    = WS + 126976;
    const unsigned short* WkT    = WS + 143360;
    const unsigned short* WvT    = WS + 159744;
    const unsigned short* WoT    = WS + 176128;
    const unsigned short* W1T    = WS + 192512;
    const unsigned short* W2T    = WS + 225280;

    f32x4 sf[3]; f32x4 af;

    // ---- prologue: stage s_i -> bufA0 ----
    ld_sa_f(s, a, row0, -1, t, sf, af);
    st_sa(bufA0, t, sf, af);
    __syncthreads();                            // P1

    // ---- s_enc = lrelu(s_i @ Wenc_s + b) ----
    f32x4 acc[2][2];
#pragma unroll
    for (int mt = 0; mt < 2; ++mt)
#pragma unroll
        for (int nt = 0; nt < 2; ++nt) acc[mt][nt] = (f32x4){0.f, 0.f, 0.f, 0.f};
    mmG<3>(WencST, 3, M0, 0, bufA0, lane, acc);
    ld_sa_f(s, a, row0, 0, t, sf, af);          // issue agent-0 staging loads
    __syncthreads();                            // P2: enc reads of bufA0 done
#pragma unroll
    for (int mt = 0; mt < 2; ++mt) {
        float4 bb = *(const float4*)(b_enc_s + M0 + mt * 16 + l4 * 4);
#pragma unroll
        for (int nt = 0; nt < 2; ++nt) {
            f32x4 v;
            v[0] = lrelu(acc[mt][nt][0] + bb.x); v[1] = lrelu(acc[mt][nt][1] + bb.y);
            v[2] = lrelu(acc[mt][nt][2] + bb.z); v[3] = lrelu(acc[mt][nt][3] + bb.w);
            *(ushort4*)(sENC + (nt * 16 + l15) * PITCH + M0 + mt * 16 + l4 * 4) = pack4v(v);
        }
    }
    st_sa(bufA1, t, sf, af);                    // staging(0) -> bufA1
    __syncthreads();                            // P3: sENC + staging(0) visible

    // ---- Q (register-resident; wave wid == head wid) ----
    f32x4 q[2][2];
#pragma unroll
    for (int mt = 0; mt < 2; ++mt)
#pragma unroll
        for (int nt = 0; nt < 2; ++nt) q[mt][nt] = (f32x4){0.f, 0.f, 0.f, 0.f};
    mmG<4>(WqT, 4, M0, 0, sENC, lane, q);

    // ---- hoist Wk/Wv fragments for the whole agent loop (64 regs) ----
    bf16x8 WkF[2][4], WvF[2][4];
    ldW<4>(WkT, 4, M0, 0, lane, WkF);
    ldW<4>(WvT, 4, M0, 0, lane, WvF);

    float4 bvf[2];
#pragma unroll
    for (int mt = 0; mt < 2; ++mt) bvf[mt] = *(const float4*)(bv + M0 + mt * 16 + l4 * 4);

    f32x4 atn[2][2];
#pragma unroll
    for (int mt = 0; mt < 2; ++mt)
#pragma unroll
        for (int nt = 0; nt < 2; ++nt) atn[mt][nt] = (f32x4){0.f, 0.f, 0.f, 0.f};
    float m_[2] = {-INFINITY, -INFINITY}, l_[2] = {0.f, 0.f};

    // merged K+V + online-softmax for one e-tile (frags in regs; single LDS pass)
    auto kv_phase = [&](const unsigned short* EB){
        f32x4 kk[2][2], vv[2][2];
#pragma unroll
        for (int mt = 0; mt < 2; ++mt)
#pragma unroll
            for (int nt = 0; nt < 2; ++nt) {
                kk[mt][nt] = (f32x4){0.f, 0.f, 0.f, 0.f};
                vv[mt][nt] = (f32x4){0.f, 0.f, 0.f, 0.f};
            }
        __builtin_amdgcn_s_setprio(1);
#pragma unroll
        for (int kc = 0; kc < 4; ++kc) {
            bf16x8 b[2];
#pragma unroll
            for (int nt = 0; nt < 2; ++nt) b[nt] = ldB(EB, nt * 16, kc, lane);
#pragma unroll
            for (int mt = 0; mt < 2; ++mt)
#pragma unroll
                for (int nt = 0; nt < 2; ++nt) {
                    kk[mt][nt] = __builtin_amdgcn_mfma_f32_16x16x32_bf16(WkF[mt][kc], b[nt], kk[mt][nt], 0, 0, 0);
                    vv[mt][nt] = __builtin_amdgcn_mfma_f32_16x16x32_bf16(WvF[mt][kc], b[nt], vv[mt][nt], 0, 0, 0);
                }
        }
        __builtin_amdgcn_s_setprio(0);
        float pr[2], corr[2];
#pragma unroll
        for (int nt = 0; nt < 2; ++nt) {
            float p = 0.f;
#pragma unroll
            for (int mt = 0; mt < 2; ++mt)
#pragma unroll
                for (int r = 0; r < 4; ++r) p = fmaf(q[mt][nt][r], kk[mt][nt][r], p);
            p += __shfl_xor(p, 16);
            p += __shfl_xor(p, 32);
            float sc = p * rsd;
            float mo = m_[nt], mn = fmaxf(mo, sc);
            pr[nt]   = __expf(sc - mn);
            corr[nt] = __expf(mo - mn);
            l_[nt] = l_[nt] * corr[nt] + pr[nt];
            m_[nt] = mn;
        }
#pragma unroll
        for (int mt = 0; mt < 2; ++mt)
#pragma unroll
            for (int nt = 0; nt < 2; ++nt)
#pragma unroll
                for (int r = 0; r < 4; ++r) {
                    float vx = lrelu(vv[mt][nt][r] + ((const float*)&bvf[mt])[r]);
                    atn[mt][nt][r] = fmaf(atn[mt][nt][r], corr[nt], pr[nt] * vx);
                }
    };

    // ---- agent loop: ONE barrier per iteration ----
    for (int n = 0; n < 7; ++n) {
        unsigned short* stageRd = (n & 1) ? bufA0 : bufA1;
        unsigned short* stageWr = (n & 1) ? bufA1 : bufA0;
        unsigned short* eWr     = (n & 1) ? sE1 : sE0;
        unsigned short* eRd     = (n & 1) ? sE0 : sE1;

        if (n < 6) ld_sa_f(s, a, row0, n + 1, t, sf, af);   // issue nt loads early
        bf16x8 F[2][4];
        ldW<4>(WsaT + n * 16384, 4, M0, 0, lane, F);        // issue Wsa(n) frags

        if (n) kv_phase(eRd);                               // KV(n-1) under the loads

        f32x4 e[2][2];
#pragma unroll
        for (int mt = 0; mt < 2; ++mt)
#pragma unroll
            for (int nt = 0; nt < 2; ++nt) e[mt][nt] = (f32x4){0.f, 0.f, 0.f, 0.f};
        mmR<4>(F, stageRd, lane, e);

#pragma unroll
        for (int mt = 0; mt < 2; ++mt) {
            float4 bb = *(const float4*)(b_enc_sa + n * 128 + M0 + mt * 16 + l4 * 4);
#pragma unroll
            for (int nt = 0; nt < 2; ++nt) {
                f32x4 v;
                v[0] = lrelu(e[mt][nt][0] + bb.x); v[1] = lrelu(e[mt][nt][1] + bb.y);
                v[2] = lrelu(e[mt][nt][2] + bb.z); v[3] = lrelu(e[mt][nt][3] + bb.w);
                *(ushort4*)(eWr + (nt * 16 + l15) * PITCH + M0 + mt * 16 + l4 * 4) = pack4v(v);
            }
        }
        if (n < 6) st_sa(stageWr, t, sf, af);
        __syncthreads();                        // the one barrier
    }
    kv_phase(sE0);                              // agent 6 (e(6) is in sE0)

    // ---- epilogue pipelining: prefetch Wo frags; h1 half-1 from sENC (stable) ----
    bf16x8 WoF[2][4];
    ldW<4>(WoT, 4, M0, 0, lane, WoF);
    f32x4 hacc[2][2];
#pragma unroll
    for (int mt = 0; mt < 2; ++mt)
#pragma unroll
        for (int nt = 0; nt < 2; ++nt) hacc[mt][nt] = (f32x4){0.f, 0.f, 0.f, 0.f};
    mmG<4>(W1T, 8, M0, 0, sENC, lane, hacc);    // h1 k=0..127 (overlaps E1 region)

    // ---- attn normalize -> bufA0 ----
#pragma unroll
    for (int mt = 0; mt < 2; ++mt)
#pragma unroll
        for (int nt = 0; nt < 2; ++nt) {
            float inv = 1.f / l_[nt];
            f32x4 v;
            v[0] = atn[mt][nt][0] * inv; v[1] = atn[mt][nt][1] * inv;
            v[2] = atn[mt][nt][2] * inv; v[3] = atn[mt][nt][3] * inv;
            *(ushort4*)(bufA0 + (nt * 16 + l15) * PITCH + M0 + mt * 16 + l4 * 4) = pack4v(v);
        }
    __syncthreads();                            // E1

    // ---- prefetch W1 half-2 frags; ov = attn @ Wo + bo -> sE0 ----
    bf16x8 W1F[2][4];
    ldW<4>(W1T, 8, M0, 4, lane, W1F);
#pragma unroll
    for (int mt = 0; mt < 2; ++mt)
#pragma unroll
        for (int nt = 0; nt < 2; ++nt) acc[mt][nt] = (f32x4){0.f, 0.f, 0.f, 0.f};
    mmR<4>(WoF, bufA0, lane, acc);
#pragma unroll
    for (int mt = 0; mt < 2; ++mt) {
        float4 bb = *(const float4*)(bo + M0 + mt * 16 + l4 * 4);
#pragma unroll
        for (int nt = 0; nt < 2; ++nt) {
            f32x4 v;
            v[0] = acc[mt][nt][0] + bb.x; v[1] = acc[mt][nt][1] + bb.y;
            v[2] = acc[mt][nt][2] + bb.z; v[3] = acc[mt][nt][3] + bb.w;
            *(ushort4*)(sE0 + (nt * 16 + l15) * PITCH + M0 + mt * 16 + l4 * 4) = pack4v(v);
        }
    }
    __syncthreads();                            // E2

    // ---- h1 half-2 (ov in sE0, frags prefetched) -> bufA0 ----
    mmR<4>(W1F, sE0, lane, hacc);
    // prefetch fc2 fragments (used after E4)
    bf16x8 a0 = ldA(W2T, 4, 0, wid, lane);
    bf16x8 a1 = ldA(W2T, 4, 16, wid, lane);
#pragma unroll
    for (int mt = 0; mt < 2; ++mt) {
        float4 bb = *(const float4*)(b_fc1 + M0 + mt * 16 + l4 * 4);
#pragma unroll
        for (int nt = 0; nt < 2; ++nt) {
            f32x4 v;
            v[0] = lrelu(hacc[mt][nt][0] + bb.x); v[1] = lrelu(hacc[mt][nt][1] + bb.y);
            v[2] = lrelu(hacc[mt][nt][2] + bb.z); v[3] = lrelu(hacc[mt][nt][3] + bb.w);
            *(ushort4*)(bufA0 + (nt * 16 + l15) * PITCH + M0 + mt * 16 + l4 * 4) = pack4v(v);
        }
    }
    __syncthreads();                            // E4: h1 visible

    // ---- all_q = h1 @ W_fc2 + b2 : wave wid takes K-chunk kc=wid ----
    float* P = (float*)(SMEM + TRB * PITCH);    // 16KB overlay on bufA1+sE0 (dead)
    {
        bf16x8 b0 = ldB(bufA0, 0, wid, lane);
        bf16x8 b1 = ldB(bufA0, 16, wid, lane);
        f32x4 z = (f32x4){0.f, 0.f, 0.f, 0.f};
        f32x4 c00 = __builtin_amdgcn_mfma_f32_16x16x32_bf16(a0, b0, z, 0, 0, 0);
        f32x4 c01 = __builtin_amdgcn_mfma_f32_16x16x32_bf16(a0, b1, z, 0, 0, 0);
        f32x4 c10 = __builtin_amdgcn_mfma_f32_16x16x32_bf16(a1, b0, z, 0, 0, 0);
        f32x4 c11 = __builtin_amdgcn_mfma_f32_16x16x32_bf16(a1, b1, z, 0, 0, 0);
        *(f32x4*)(P + wid * 1024 + (l15     ) * 32 +      l4 * 4) = c00;
        *(f32x4*)(P + wid * 1024 + (16 + l15) * 32 +      l4 * 4) = c01;
        *(f32x4*)(P + wid * 1024 + (l15     ) * 32 + 16 + l4 * 4) = c10;
        *(f32x4*)(P + wid * 1024 + (16 + l15) * 32 + 16 + l4 * 4) = c11;
    }
    __syncthreads();                            // E5

    float* S = (float*)sENC;                    // stash [32][33] overlay (sENC dead)
#pragma unroll
    for (int j = 0; j < 4; ++j) {
        int o = t + 256 * j; int row = o >> 5, f = o & 31;
        float v = P[row * 32 + f] + P[1024 + row * 32 + f]
                + P[2048 + row * 32 + f] + P[3072 + row * 32 + f] + b_fc2[f];
        out_allq[(size_t)(row0 + row) * 32 + f] = v;
        S[row * 33 + f] = v;
    }
    __syncthreads();                            // E6

    // ---- q = all_q[argmax(a[:, :32])] ----
    if (t < TRB) {
        int row = row0 + t;
        float best = -INFINITY; int bi = 0;
#pragma unroll
        for (int jj = 0; jj < 8; ++jj) {
            f32x4 v = ldg_nt4(a + (size_t)row * 256 + jj * 4);
#pragma unroll
            for (int e2 = 0; e2 < 4; ++e2)
                if (v[e2] > best) { best = v[e2]; bi = jj * 4 + e2; }
        }
        out_q[row] = S[t * 33 + bi];
    }
}

extern "C" void kernel_launch(void* const* d_in, const int* in_sizes, int n_in,
                              void* d_out, int out_size, void* d_ws, size_t ws_size,
                              hipStream_t stream)
{
    (void)n_in; (void)out_size; (void)ws_size;
    const float* s        = (const float*)d_in[0];
    const float* a        = (const float*)d_in[1];
    const float* W_enc_s  = (const float*)d_in[2];
    const float* b_enc_s  = (const float*)d_in[3];
    const float* W_enc_sa = (const float*)d_in[4];
    const float* b_enc_sa = (const float*)d_in[5];
    const float* Wq       = (const float*)d_in[6];
    const float* Wk       = (const float*)d_in[7];
    const float* Wv       = (const float*)d_in[8];
    const float* bv       = (const float*)d_in[9];
    const float* Wo       = (const float*)d_in[10];
    const float* bo       = (const float*)d_in[11];
    const float* W_fc1    = (const float*)d_in[12];
    const float* b_fc1    = (const float*)d_in[13];
    const float* W_fc2    = (const float*)d_in[14];
    const float* b_fc2    = (const float*)d_in[15];

    int B = in_sizes[0] / 768;
    float* out_q    = (float*)d_out;
    float* out_allq = out_q + B;
    unsigned short* WS = (unsigned short*)d_ws;

    wprep<<<dim3(896), dim3(256), 0, stream>>>(W_enc_s, W_enc_sa, Wq, Wk, Wv, Wo,
                                               W_fc1, W_fc2, WS);
    ac_mfma<<<dim3(B / TRB), dim3(256), 0, stream>>>(s, a, WS, b_enc_s, b_enc_sa,
                                                     bv, bo, b_fc1, b_fc2,
                                                     out_q, out_allq);
}